// Round 1
// baseline (151.525 us; speedup 1.0000x reference)
//
#include <hip/hip_runtime.h>

// MLPDecoder: out[e, c] = sum_d |input[r[e],d] - input[c[e],d]| * W[d,c]
// N_NODES=100000, D=256, N_EDGES=500000, N_CLASSES=4
// Structure: one wave (64 lanes) per edge; lane i handles dims [4i, 4i+4).
// Per-lane: 2x float4 gather loads (coalesced 1KB/row per wave), 4x abs-diff,
// 16 FMAs against register-resident weight rows, then 6-stage shfl_xor
// butterfly reduce of the 4 class accumulators; lane 0 writes float4.

#define NODES   100000
#define DIM     256
#define EDGES   500000
#define NCLS    4

__global__ __launch_bounds__(256, 8) void edge_mlp_kernel(
    const float* __restrict__ input,     // [NODES, DIM]
    const int*   __restrict__ r_idx,     // [EDGES]
    const int*   __restrict__ c_idx,     // [EDGES]
    const float* __restrict__ weight,    // [DIM, NCLS]
    float*       __restrict__ out)       // [EDGES, NCLS]
{
    const int lane = threadIdx.x & 63;
    const int wave_in_block = threadIdx.x >> 6;
    const int waves_per_block = blockDim.x >> 6;
    const int wave_id = blockIdx.x * waves_per_block + wave_in_block;
    const int n_waves = gridDim.x * waves_per_block;

    // Preload this lane's 4 weight rows (dims 4*lane .. 4*lane+3), 4 classes each.
    const int d0 = lane * 4;
    const float4 w0 = *(const float4*)(weight + (d0 + 0) * NCLS);
    const float4 w1 = *(const float4*)(weight + (d0 + 1) * NCLS);
    const float4 w2 = *(const float4*)(weight + (d0 + 2) * NCLS);
    const float4 w3 = *(const float4*)(weight + (d0 + 3) * NCLS);

    for (int e = wave_id; e < EDGES; e += n_waves) {
        const int r = r_idx[e];
        const int c = c_idx[e];
        const float4 a = *(const float4*)(input + (size_t)r * DIM + d0);
        const float4 b = *(const float4*)(input + (size_t)c * DIM + d0);

        const float t0 = fabsf(a.x - b.x);
        const float t1 = fabsf(a.y - b.y);
        const float t2 = fabsf(a.z - b.z);
        const float t3 = fabsf(a.w - b.w);

        float4 acc;
        acc.x = t0 * w0.x + t1 * w1.x + t2 * w2.x + t3 * w3.x;
        acc.y = t0 * w0.y + t1 * w1.y + t2 * w2.y + t3 * w3.y;
        acc.z = t0 * w0.z + t1 * w1.z + t2 * w2.z + t3 * w3.z;
        acc.w = t0 * w0.w + t1 * w1.w + t2 * w2.w + t3 * w3.w;

        // Butterfly reduce across the 64-lane wave.
        #pragma unroll
        for (int m = 32; m >= 1; m >>= 1) {
            acc.x += __shfl_xor(acc.x, m, 64);
            acc.y += __shfl_xor(acc.y, m, 64);
            acc.z += __shfl_xor(acc.z, m, 64);
            acc.w += __shfl_xor(acc.w, m, 64);
        }

        if (lane == 0) {
            *(float4*)(out + (size_t)e * NCLS) = acc;
        }
    }
}

extern "C" void kernel_launch(void* const* d_in, const int* in_sizes, int n_in,
                              void* d_out, int out_size, void* d_ws, size_t ws_size,
                              hipStream_t stream) {
    const float* input  = (const float*)d_in[0];
    const int*   r_idx  = (const int*)d_in[1];
    const int*   c_idx  = (const int*)d_in[2];
    const float* weight = (const float*)d_in[3];
    float* out = (float*)d_out;

    // 2048 blocks x 256 threads = 8192 waves = full residency (256 CU x 32 w/CU).
    dim3 grid(2048), block(256);
    edge_mlp_kernel<<<grid, block, 0, stream>>>(input, r_idx, c_idx, weight, out);
}

// Round 2
// 149.656 us; speedup vs baseline: 1.0125x; 1.0125x over previous
//
#include <hip/hip_runtime.h>

// MLPDecoder: out[e, c] = sum_d |input[r[e],d] - input[c[e],d]| * W[d,c]
// N_NODES=100000, D=256, N_EDGES=500000, N_CLASSES=4
//
// R2: one wave per EDGE-PAIR, software-pipelined.
//  - 4 independent 1KB row gathers in flight per iteration (2 edges).
//  - Next iteration's 4 index loads issued before the current compute,
//    hiding index latency under row-load latency + reduce.
//  - Lane i covers dims [4i,4i+4); per-lane weight rows in registers.
//  - Butterfly reduce both edges (independent shfl chains -> ILP);
//    lanes 0/1 store the two float4 results (32B contiguous).

#define NODES   100000
#define DIM     256
#define EDGES   500000   // even -> pair processing has no tail
#define NCLS    4

__global__ __launch_bounds__(256, 8) void edge_mlp_kernel(
    const float* __restrict__ input,     // [NODES, DIM]
    const int*   __restrict__ r_idx,     // [EDGES]
    const int*   __restrict__ c_idx,     // [EDGES]
    const float* __restrict__ weight,    // [DIM, NCLS]
    float*       __restrict__ out)       // [EDGES, NCLS]
{
    const int lane = threadIdx.x & 63;
    const int wave_in_block = threadIdx.x >> 6;
    const int waves_per_block = blockDim.x >> 6;
    const int wave_id = blockIdx.x * waves_per_block + wave_in_block;
    const int n_waves = gridDim.x * waves_per_block;
    const int step = n_waves * 2;

    // Per-lane weight rows (dims 4*lane .. 4*lane+3), 4 classes each.
    const int d0 = lane * 4;
    const float4 w0 = *(const float4*)(weight + (d0 + 0) * NCLS);
    const float4 w1 = *(const float4*)(weight + (d0 + 1) * NCLS);
    const float4 w2 = *(const float4*)(weight + (d0 + 2) * NCLS);
    const float4 w3 = *(const float4*)(weight + (d0 + 3) * NCLS);

    int e = wave_id * 2;
    if (e >= EDGES) return;

    // Prologue: indices for the first pair.
    int r0 = r_idx[e],     c0 = c_idx[e];
    int r1 = r_idx[e + 1], c1 = c_idx[e + 1];

    while (true) {
        // Issue all 4 row gathers (independent, 1KB coalesced each).
        const float4 a0 = *(const float4*)(input + (size_t)r0 * DIM + d0);
        const float4 b0 = *(const float4*)(input + (size_t)c0 * DIM + d0);
        const float4 a1 = *(const float4*)(input + (size_t)r1 * DIM + d0);
        const float4 b1 = *(const float4*)(input + (size_t)c1 * DIM + d0);

        // Prefetch next pair's indices under the row-load latency.
        const int en = e + step;
        const bool more = (en < EDGES);
        int nr0, nc0, nr1, nc1;
        if (more) {
            nr0 = r_idx[en];     nc0 = c_idx[en];
            nr1 = r_idx[en + 1]; nc1 = c_idx[en + 1];
        }

        // Edge 0 partials.
        const float s0 = fabsf(a0.x - b0.x);
        const float s1 = fabsf(a0.y - b0.y);
        const float s2 = fabsf(a0.z - b0.z);
        const float s3 = fabsf(a0.w - b0.w);
        // Edge 1 partials.
        const float t0 = fabsf(a1.x - b1.x);
        const float t1 = fabsf(a1.y - b1.y);
        const float t2 = fabsf(a1.z - b1.z);
        const float t3 = fabsf(a1.w - b1.w);

        float4 acc0, acc1;
        acc0.x = s0 * w0.x + s1 * w1.x + s2 * w2.x + s3 * w3.x;
        acc0.y = s0 * w0.y + s1 * w1.y + s2 * w2.y + s3 * w3.y;
        acc0.z = s0 * w0.z + s1 * w1.z + s2 * w2.z + s3 * w3.z;
        acc0.w = s0 * w0.w + s1 * w1.w + s2 * w2.w + s3 * w3.w;
        acc1.x = t0 * w0.x + t1 * w1.x + t2 * w2.x + t3 * w3.x;
        acc1.y = t0 * w0.y + t1 * w1.y + t2 * w2.y + t3 * w3.y;
        acc1.z = t0 * w0.z + t1 * w1.z + t2 * w2.z + t3 * w3.z;
        acc1.w = t0 * w0.w + t1 * w1.w + t2 * w2.w + t3 * w3.w;

        // Two independent butterfly chains (ILP in the shfl stages).
        #pragma unroll
        for (int m = 32; m >= 1; m >>= 1) {
            acc0.x += __shfl_xor(acc0.x, m, 64);
            acc1.x += __shfl_xor(acc1.x, m, 64);
            acc0.y += __shfl_xor(acc0.y, m, 64);
            acc1.y += __shfl_xor(acc1.y, m, 64);
            acc0.z += __shfl_xor(acc0.z, m, 64);
            acc1.z += __shfl_xor(acc1.z, m, 64);
            acc0.w += __shfl_xor(acc0.w, m, 64);
            acc1.w += __shfl_xor(acc1.w, m, 64);
        }

        // After the butterfly every lane holds the full sums: lanes 0 and 1
        // store the two edges -> one contiguous 32B segment.
        if (lane == 0) {
            *(float4*)(out + (size_t)e * NCLS) = acc0;
        } else if (lane == 1) {
            *(float4*)(out + (size_t)(e + 1) * NCLS) = acc1;
        }

        if (!more) break;
        e = en;
        r0 = nr0; c0 = nc0; r1 = nr1; c1 = nc1;
    }
}

extern "C" void kernel_launch(void* const* d_in, const int* in_sizes, int n_in,
                              void* d_out, int out_size, void* d_ws, size_t ws_size,
                              hipStream_t stream) {
    const float* input  = (const float*)d_in[0];
    const int*   r_idx  = (const int*)d_in[1];
    const int*   c_idx  = (const int*)d_in[2];
    const float* weight = (const float*)d_in[3];
    float* out = (float*)d_out;

    // 2048 blocks x 256 threads = 8192 waves = full residency (256 CU x 32 w/CU).
    dim3 grid(2048), block(256);
    edge_mlp_kernel<<<grid, block, 0, stream>>>(input, r_idx, c_idx, weight, out);
}